// Round 3
// baseline (466.182 us; speedup 1.0000x reference)
//
#include <hip/hip_runtime.h>
#include <math.h>

#define N_TOK 16384
#define HDIM  2048
#define NEXP  64
#define TOPK  8

// d_ws layout:
//   [0, 1 MiB)            : Wd   — weight converted to f64 (131072 doubles)
//   [1 MiB, 17 MiB)       : part — partial logits f64 [2][N_TOK][64]
//   [17 MiB + ...]        : stats — f32 probsum[64], counts[64]
#define WD_OFF    0
#define PART_OFF  (1u << 20)
#define STATS_OFF ((1u << 20) + (16u << 20))

__global__ __launch_bounds__(256) void conv_w_kernel(const float* __restrict__ W,
                                                     double* __restrict__ Wd) {
    int i = blockIdx.x * 256 + threadIdx.x;          // grid 512*256 = 131072
    Wd[i] = (double)W[i];
}

// GEMM partial: block = (token-tile of 64) x (H half of 1024).
// 256 threads: wave q handles experts [16q,16q+16) for all 64 tokens; lane = token.
__global__ __launch_bounds__(256) void gemm_part_kernel(const float* __restrict__ X,
                                                        const double* __restrict__ Wd,
                                                        double* __restrict__ part) {
    const int tt  = blockIdx.x >> 1;
    const int hs  = blockIdx.x & 1;
    const int tid = threadIdx.x;
    const int tl  = tid & 63;                        // token lane
    const int e0  = __builtin_amdgcn_readfirstlane((tid >> 6) * 16);  // wave-uniform
    const int tok0  = tt * 64;
    const int hbase = hs * 1024;

    __shared__ float xs[64][36];                     // pad 36: b128 reads 2-way (free)

    double acc[16];
#pragma unroll
    for (int e = 0; e < 16; ++e) acc[e] = 0.0;

    // cooperative staging coords: thread loads rows r0 and r0+32, 4 floats at col c0
    const int r0 = tid >> 3;
    const int c0 = (tid & 7) * 4;
    const float* xbase = X + (size_t)tok0 * HDIM + hbase;

    float4 pf0 = *(const float4*)(xbase + (size_t)r0        * HDIM + c0);
    float4 pf1 = *(const float4*)(xbase + (size_t)(r0 + 32) * HDIM + c0);

    for (int c = 0; c < 32; ++c) {                   // 32 chunks of 32 h
        __syncthreads();                             // readers of previous chunk done
        *(float4*)&xs[r0][c0]      = pf0;
        *(float4*)&xs[r0 + 32][c0] = pf1;
        __syncthreads();
        if (c < 31) {                                // prefetch next chunk (regs)
            const float* nb = xbase + (c + 1) * 32;
            pf0 = *(const float4*)(nb + (size_t)r0        * HDIM + c0);
            pf1 = *(const float4*)(nb + (size_t)(r0 + 32) * HDIM + c0);
        }
        const double* wp = Wd + (size_t)e0 * HDIM + hbase + c * 32;   // uniform -> s_load
#pragma unroll
        for (int h4 = 0; h4 < 8; ++h4) {
            float4 xv = *(const float4*)&xs[tl][h4 * 4];
            double x0 = (double)xv.x, x1 = (double)xv.y;
            double x2 = (double)xv.z, x3 = (double)xv.w;
#pragma unroll
            for (int e = 0; e < 16; ++e) {
                const double* w4 = wp + (size_t)e * HDIM + h4 * 4;
                acc[e] = fma(x0, w4[0], acc[e]);
                acc[e] = fma(x1, w4[1], acc[e]);
                acc[e] = fma(x2, w4[2], acc[e]);
                acc[e] = fma(x3, w4[3], acc[e]);
            }
        }
    }

    double* pout = part + ((size_t)hs * N_TOK + tok0 + tl) * NEXP + e0;
#pragma unroll
    for (int e = 0; e < 16; e += 2) {
        double2 v; v.x = acc[e]; v.y = acc[e + 1];
        *(double2*)(pout + e) = v;
    }
}

// Top-k probe, selection domain = FLOAT32 SCORES (correctly-rounded sigmoid
// of the exact f64 logit), strict > ascending scan => lower index wins f32
// ties — matches jax.lax.top_k's stable ordering on f32 score arrays.
__global__ __launch_bounds__(256) void topk_simple_kernel(const double* __restrict__ part,
                                                          float* __restrict__ outIdx,
                                                          float* __restrict__ outW,
                                                          float* __restrict__ stats) {
    __shared__ float lcnt[NEXP];
    __shared__ float lps[NEXP];
    const int tid = threadIdx.x;
    if (tid < NEXP) { lcnt[tid] = 0.f; lps[tid] = 0.f; }
    __syncthreads();

    const int t = blockIdx.x * 256 + tid;            // grid 64*256 = 16384

    float s[NEXP];
    float rowsum = 0.f;
    for (int e = 0; e < NEXP; ++e) {
        double v = part[(size_t)t * NEXP + e] + part[((size_t)N_TOK + t) * NEXP + e];
        // correctly-rounded f32 sigmoid: one rounding, from f64 evaluation
        float sv = (float)(1.0 / (1.0 + exp(-v)));
        s[e] = sv;
        rowsum += sv;
    }
    const float inv_rs = 1.f / (rowsum + 1e-9f);
    for (int e = 0; e < NEXP; ++e) atomicAdd(&lps[e], s[e] * inv_rs);

    unsigned long long chosen = 0ull;
    int   idxs[TOPK];
    float wvs[TOPK];
    float denom = 0.f;
    for (int k = 0; k < TOPK; ++k) {
        float best = -1.f;
        int   bi   = 0;
        for (int e = 0; e < NEXP; ++e) {
            if ((chosen >> e) & 1ull) continue;
            if (s[e] > best) { best = s[e]; bi = e; }  // strict: lowest index on f32 tie
        }
        chosen |= 1ull << bi;
        idxs[k] = bi;
        wvs[k]  = s[bi];
        denom  += s[bi];
    }
    const float inv_d = 1.f / (denom + 1e-9f);
    for (int k = 0; k < TOPK; ++k) {
        outIdx[(size_t)t * TOPK + k] = (float)idxs[k];
        outW [(size_t)t * TOPK + k] = wvs[k] * inv_d;
        atomicAdd(&lcnt[idxs[k]], 1.f);
    }
    __syncthreads();
    if (tid < NEXP) {
        atomicAdd(&stats[tid],        lps[tid]);     // probsum
        atomicAdd(&stats[NEXP + tid], lcnt[tid]);    // counts
    }
}

__global__ void aux_kernel(const float* __restrict__ stats, float* __restrict__ out) {
    const int e = threadIdx.x;                                // 64 threads
    float prob = stats[e] / (float)N_TOK;
    float cnt  = stats[NEXP + e];
    float loadf = cnt / ((float)N_TOK * TOPK);
    float S = prob;
#pragma unroll
    for (int off = 32; off; off >>= 1) S += __shfl_xor(S, off);
    float pn = prob / (S + 1e-9f);
    float v  = loadf * pn;
#pragma unroll
    for (int off = 32; off; off >>= 1) v += __shfl_xor(v, off);
    if (e == 0) out[2 * N_TOK * TOPK] = 0.001f * v * (float)NEXP;
}

extern "C" void kernel_launch(void* const* d_in, const int* in_sizes, int n_in,
                              void* d_out, int out_size, void* d_ws, size_t ws_size,
                              hipStream_t stream) {
    (void)in_sizes; (void)n_in; (void)out_size; (void)ws_size;
    const float* X = (const float*)d_in[0];
    const float* W = (const float*)d_in[1];
    float* out = (float*)d_out;
    char*  ws  = (char*)d_ws;
    double* Wd    = (double*)(ws + WD_OFF);
    double* part  = (double*)(ws + PART_OFF);
    float*  stats = (float*)(ws + STATS_OFF);

    hipMemsetAsync(stats, 0, 128 * sizeof(float), stream);
    conv_w_kernel<<<512, 256, 0, stream>>>(W, Wd);
    gemm_part_kernel<<<512, 256, 0, stream>>>(X, Wd, part);
    topk_simple_kernel<<<64, 256, 0, stream>>>(part, out, out + N_TOK * TOPK, stats);
    aux_kernel<<<1, 64, 0, stream>>>(stats, out);
}

// Round 4
// 237.643 us; speedup vs baseline: 1.9617x; 1.9617x over previous
//
#include <hip/hip_runtime.h>
#include <math.h>

#define N_TOK 16384
#define HDIM  2048
#define NEXP  64
#define TOPK  8
#define NHS   4            // H split factor
#define HSEG  (HDIM / NHS) // 512

// d_ws layout:
//   [0, 1 MiB)        : Wd    — weight as f64 [64][2048]
//   [1 MiB, 33 MiB)   : part  — partial logits f64 [NHS][N_TOK][64]
//   [33 MiB, ...)     : stats — f32 probsum[64], counts[64]
#define WD_OFF    0
#define PART_OFF  (1u << 20)
#define STATS_OFF (33u << 20)

__global__ __launch_bounds__(256) void conv_w_kernel(const float* __restrict__ W,
                                                     double* __restrict__ Wd) {
    int i = blockIdx.x * 256 + threadIdx.x;          // grid 512*256 = 131072
    Wd[i] = (double)W[i];
}

// GEMM partial: grid = 256 token-tiles x 4 H-segments, block = 512 threads (8 waves).
// lane = token (64 tokens/block); wave w handles experts [8w, 8w+8).
// Weights via wave-uniform s_load (8 experts -> small scalar working set,
// pipelinable); 100% occupancy (4 blocks/CU = 32 waves/CU) hides the rest.
__global__ __launch_bounds__(512) void gemm_part_kernel(const float* __restrict__ X,
                                                        const double* __restrict__ Wd,
                                                        double* __restrict__ part) {
    const int tt  = blockIdx.x >> 2;
    const int hs  = blockIdx.x & 3;
    const int tid = threadIdx.x;
    const int tl  = tid & 63;                        // token lane
    const int e0  = __builtin_amdgcn_readfirstlane((tid >> 6) * 8);  // wave-uniform
    const int tok0  = tt * 64;
    const int hbase = hs * HSEG;

    __shared__ float xs[64][36];                     // pad 36: b128 reads 2-way (free)

    double acc[8];
#pragma unroll
    for (int e = 0; e < 8; ++e) acc[e] = 0.0;

    // staging: 512 threads cover [64 tokens][32 h] exactly, 1 float4 each
    const int r0 = tid >> 3;
    const int c0 = (tid & 7) * 4;
    const float* xbase = X + (size_t)tok0 * HDIM + hbase;

    float4 pf = *(const float4*)(xbase + (size_t)r0 * HDIM + c0);

    for (int c = 0; c < HSEG / 32; ++c) {            // 16 chunks of 32 h
        __syncthreads();                             // readers of previous chunk done
        *(float4*)&xs[r0][c0] = pf;
        __syncthreads();
        if (c < HSEG / 32 - 1) {                     // prefetch next chunk into regs
            pf = *(const float4*)(xbase + (size_t)r0 * HDIM + (c + 1) * 32 + c0);
        }
        const double* wp = Wd + (size_t)e0 * HDIM + hbase + c * 32;   // uniform -> s_load
#pragma unroll
        for (int h4 = 0; h4 < 8; ++h4) {
            float4 xv = *(const float4*)&xs[tl][h4 * 4];
            double x0 = (double)xv.x, x1 = (double)xv.y;
            double x2 = (double)xv.z, x3 = (double)xv.w;
#pragma unroll
            for (int e = 0; e < 8; ++e) {
                const double* w4 = wp + (size_t)e * HDIM + h4 * 4;
                acc[e] = fma(x0, w4[0], acc[e]);
                acc[e] = fma(x1, w4[1], acc[e]);
                acc[e] = fma(x2, w4[2], acc[e]);
                acc[e] = fma(x3, w4[3], acc[e]);
            }
        }
    }

    double* pout = part + ((size_t)hs * N_TOK + tok0 + tl) * NEXP + e0;
#pragma unroll
    for (int e = 0; e < 8; e += 2) {
        double2 v; v.x = acc[e]; v.y = acc[e + 1];
        *(double2*)(pout + e) = v;
    }
}

// Top-k: wave-parallel, lane = expert. Comparator = f32 score (correctly-
// rounded sigmoid of exact f64 logit), ties -> lower index; verified
// bit-identical to the serial probe's selection on this dataset.
// Block = 4 waves x 16 tokens; grid 256.
__global__ __launch_bounds__(256) void topk_kernel(const double* __restrict__ part,
                                                   float* __restrict__ outIdx,
                                                   float* __restrict__ outW,
                                                   float* __restrict__ stats) {
    __shared__ float lds_counts[NEXP];
    __shared__ float psum_part[4][NEXP];
    const int tid  = threadIdx.x;
    const int lane = tid & 63;
    const int w    = tid >> 6;
    if (tid < NEXP) lds_counts[tid] = 0.f;
    __syncthreads();

    float ps = 0.f;
    const int t0 = blockIdx.x * 64 + w * 16;
    for (int i = 0; i < 16; ++i) {
        const int t = t0 + i;
        const double* p = part + (size_t)t * NEXP + lane;
        double l = (p[0]                        + p[(size_t)N_TOK * NEXP]) +
                   (p[2 * (size_t)N_TOK * NEXP] + p[3 * (size_t)N_TOK * NEXP]);
        float s = (float)(1.0 / (1.0 + exp(-l)));     // one rounding to f32

        float rs = s;
#pragma unroll
        for (int off = 32; off; off >>= 1) rs += __shfl_xor(rs, off);
        ps += s / (rs + 1e-9f);

        float cur = s;                                // masked working copy
        float denom = 0.f;
        int   wi = 0;
        float wv = 0.f;
#pragma unroll
        for (int k = 0; k < TOPK; ++k) {
            float m = cur; int mi = lane;
#pragma unroll
            for (int off = 32; off; off >>= 1) {      // argmax, ties -> min idx
                float om = __shfl_xor(m, off);
                int   oi = __shfl_xor(mi, off);
                if (om > m || (om == m && oi < mi)) { m = om; mi = oi; }
            }
            denom += m;
            if (lane == k)  { wi = mi; wv = m; }
            if (lane == mi) cur = -1e30f;             // mask winner
        }
        if (lane < TOPK) {
            outIdx[(size_t)t * TOPK + lane] = (float)wi;
            outW  [(size_t)t * TOPK + lane] = wv / (denom + 1e-9f);
            atomicAdd(&lds_counts[wi], 1.f);
        }
    }
    psum_part[w][lane] = ps;
    __syncthreads();
    if (tid < NEXP) {
        float tot = psum_part[0][tid] + psum_part[1][tid] +
                    psum_part[2][tid] + psum_part[3][tid];
        atomicAdd(&stats[tid], tot);                  // probsum
        atomicAdd(&stats[NEXP + tid], lds_counts[tid]); // counts
    }
}

__global__ void aux_kernel(const float* __restrict__ stats, float* __restrict__ out) {
    const int e = threadIdx.x;                        // 64 threads
    float prob = stats[e] / (float)N_TOK;
    float cnt  = stats[NEXP + e];
    float loadf = cnt / ((float)N_TOK * TOPK);
    float S = prob;
#pragma unroll
    for (int off = 32; off; off >>= 1) S += __shfl_xor(S, off);
    float pn = prob / (S + 1e-9f);
    float v  = loadf * pn;
#pragma unroll
    for (int off = 32; off; off >>= 1) v += __shfl_xor(v, off);
    if (e == 0) out[2 * N_TOK * TOPK] = 0.001f * v * (float)NEXP;
}

extern "C" void kernel_launch(void* const* d_in, const int* in_sizes, int n_in,
                              void* d_out, int out_size, void* d_ws, size_t ws_size,
                              hipStream_t stream) {
    (void)in_sizes; (void)n_in; (void)out_size; (void)ws_size;
    const float* X = (const float*)d_in[0];
    const float* W = (const float*)d_in[1];
    float* out = (float*)d_out;
    char*  ws  = (char*)d_ws;
    double* Wd    = (double*)(ws + WD_OFF);
    double* part  = (double*)(ws + PART_OFF);
    float*  stats = (float*)(ws + STATS_OFF);

    hipMemsetAsync(stats, 0, 128 * sizeof(float), stream);
    conv_w_kernel<<<512, 256, 0, stream>>>(W, Wd);
    gemm_part_kernel<<<1024, 512, 0, stream>>>(X, Wd, part);
    topk_kernel<<<256, 256, 0, stream>>>(part, out, out + N_TOK * TOPK, stats);
    aux_kernel<<<1, 64, 0, stream>>>(stats, out);
}